// Round 5
// baseline (270.265 us; speedup 1.0000x reference)
//
#include <hip/hip_runtime.h>
#include <math.h>

// SpatialSampler: B=256, A=64, k=64, P=32, BETA=0.1
// out = [places (33.55M f32) | sampled_points (33.55M f32)]
//   places[bp,j,k]  = h[bp,j] * v[bp,k]
//   sampled[bp,j,k] = 100*h[jmax]*v[kmax] at (jmax,kmax), else 0
//
// Single fused kernel, one wave per bp (8192 waves = 2048 blocks x 256):
//   - wave loads its 512B x-row + 512B noise-row once (coalesced)
//   - streams its 16KB places tile (16 x dwordx4/lane, deps only on x loads)
//   - in-wave shuffle argmax overlaps the places stores (independent chains)
//   - streams its 16KB sampled tile with the one nonzero value blended in
// No LDS, no barrier, no second kernel. 268 MB stores / 8 MB loads.
// NOTE: harness's 0xAA re-poison (1 GiB fill, ~166 us) is inside the timed
// window — the controllable budget is only the ~76 us above that floor.

#define BETA 0.1f
#define PLACES_ELEMS 33554432ull   // 256*32*64*64

typedef float vfloat4 __attribute__((ext_vector_type(4)));

__global__ __launch_bounds__(256) void spatial_fused(
    const float* __restrict__ x_cat,
    const float* __restrict__ noise,
    float* __restrict__ out)
{
    const int bp   = blockIdx.x * 4 + (threadIdx.x >> 6);  // wave id = bp
    const int lane = threadIdx.x & 63;

    const float* xrow = x_cat + (size_t)bp * 128;
    const float* nrow = noise + (size_t)bp * 128;

    const float h = xrow[lane];        // lane's h element
    const float v = xrow[64 + lane];   // lane's v element

    // ---- places: 1024 f4 tile; iter i writes f4 [i*64+lane] (1KB/wave/instr)
    // f = i*64+lane -> row j = i*4 + (lane>>4), col-quad c = lane&15 (invariant)
    vfloat4* __restrict__ pl = (vfloat4*)out + (size_t)bp * 1024;
    const int jb = lane >> 4;
    const int c4 = (lane & 15) * 4;
    vfloat4 v4;
    v4.x = __shfl(v, c4 + 0, 64);
    v4.y = __shfl(v, c4 + 1, 64);
    v4.z = __shfl(v, c4 + 2, 64);
    v4.w = __shfl(v, c4 + 3, 64);
    #pragma unroll
    for (int i = 0; i < 16; ++i) {
        const float hj = __shfl(h, i * 4 + jb, 64);   // in-reg broadcast
        pl[i * 64 + lane] = hj * v4;
    }

    // ---- argmax over log(x) + BETA*noise for h and v (bit-identical to R4)
    float lph = logf(h) + BETA * nrow[lane];
    float lpv = logf(v) + BETA * nrow[64 + lane];
    int   jh  = lane;
    int   jv  = lane;
    #pragma unroll
    for (int off = 32; off > 0; off >>= 1) {
        const float oh = __shfl_xor(lph, off, 64);
        const int   oi = __shfl_xor(jh,  off, 64);
        const float ov = __shfl_xor(lpv, off, 64);
        const int   oj = __shfl_xor(jv,  off, 64);
        if (oh > lph || (oh == lph && oi < jh)) { lph = oh; jh = oi; }
        if (ov > lpv || (ov == lpv && oj < jv)) { lpv = ov; jv = oj; }
    }
    const float val  = 100.0f * __shfl(h, jh, 64) * __shfl(v, jv, 64);
    const int   eidx = jh * 64 + jv;     // nonzero element index in [0,4096)
    const int   if4  = eidx >> 2;        // its f4 index
    const int   sub  = eidx & 3;

    // ---- sampled: 1024 f4 tile of zeros with one value blended in
    vfloat4* __restrict__ sp = (vfloat4*)(out + PLACES_ELEMS) + (size_t)bp * 1024;
    #pragma unroll
    for (int i = 0; i < 16; ++i) {
        const int f = i * 64 + lane;
        vfloat4 z = {0.f, 0.f, 0.f, 0.f};
        if (f == if4) {                  // exactly one lane, one iter
            z.x = (sub == 0) ? val : 0.f;
            z.y = (sub == 1) ? val : 0.f;
            z.z = (sub == 2) ? val : 0.f;
            z.w = (sub == 3) ? val : 0.f;
        }
        sp[f] = z;
    }
}

extern "C" void kernel_launch(void* const* d_in, const int* in_sizes, int n_in,
                              void* d_out, int out_size, void* d_ws, size_t ws_size,
                              hipStream_t stream) {
    const float* x_cat = (const float*)d_in[0];
    const float* noise = (const float*)d_in[1];
    float* out = (float*)d_out;

    // 8192 waves (one per bp) = 2048 blocks x 256 threads.
    spatial_fused<<<dim3(2048), dim3(256), 0, stream>>>(x_cat, noise, out);
}